// Round 17
// baseline (849.349 us; speedup 1.0000x reference)
//
#include <hip/hip_runtime.h>
#include <hip/hip_bf16.h>

using bf16 = __hip_bfloat16;
typedef __attribute__((ext_vector_type(8))) short s8v;
typedef __attribute__((ext_vector_type(4))) float f4v;
#define DEVINL __device__ __forceinline__

constexpr int B_ = 4, C_ = 8, H_ = 240, W_ = 240;
constexpr int P_ = 10, S_ = 5, K_ = 7;
constexpr int G_ = 47, M_ = G_ * G_, O2_ = 225, D_ = 800;
constexpr int HW_ = H_ * W_;
constexpr int NC_ = 48;
constexpr int ND_ = 16;
constexpr int ASTR_ = NC_ * ND_ * 7;
constexpr int CFSTR_ = 3 * 7 * 2 * 512;          // cellfrag shorts per (b,ci) = 21504
constexpr size_t CTSZ_ = (size_t)B_ * 48 * 15 * 2304;   // Ctab floats

DEVINL float loadf(const void* p, size_t i, int isf32) {
  return isf32 ? ((const float*)p)[i] : __bfloat162float(((const bf16*)p)[i]);
}
DEVINL int wsg(int g) { int s = g - 7; if (s < 0) s = 0; if (s > G_ - 15) s = G_ - 15; return s; }
DEVINL ushort bf16rn(float x) {
  uint u = __float_as_uint(x);
  return (ushort)((u + 0x7FFF + ((u >> 16) & 1)) >> 16);
}

// ---- block reductions (256 threads, wave64) ----
DEVINL float bredsum(float v, float* red, int t) {
#pragma unroll
  for (int off = 32; off; off >>= 1) v += __shfl_xor(v, off);
  __syncthreads();
  if ((t & 63) == 0) red[t >> 6] = v;
  __syncthreads();
  return red[0] + red[1] + red[2] + red[3];
}

// ---- dtype detector (flag=1 => f32 inputs) ----
__global__ __launch_bounds__(256) void detect_k(const ushort* __restrict__ xr, int* __restrict__ flag) {
  __shared__ int red[4];
  const int t = threadIdx.x;
  int wild = 0;
  for (int i = t; i < 8192; i += 256) {
    const ushort u = xr[2 * i];
    const int ex = (u >> 7) & 0xFF;
    if (ex == 0xFF || ex > 130 || (ex != 0 && ex < 100)) ++wild;
  }
#pragma unroll
  for (int off = 32; off; off >>= 1) wild += __shfl_xor(wild, off);
  __syncthreads();
  if ((t & 63) == 0) red[t >> 6] = wild;
  __syncthreads();
  if (t == 0) flag[0] = (red[0] + red[1] + red[2] + red[3] > 2048) ? 1 : 0;
}

__global__ __launch_bounds__(256) void cvt_x_k(const void* __restrict__ x, const int* __restrict__ flag,
                                               float* __restrict__ xf) {
  const int i = blockIdx.x * 256 + threadIdx.x;
  xf[i] = loadf(x, i, flag[0]);
}

// ---- channels-last copy: xfc[b][pix][8] from planar xf ----
__global__ __launch_bounds__(256) void cvt2_k(const float* __restrict__ xf, float* __restrict__ xfc) {
  const int pg = blockIdx.x * 256 + threadIdx.x;   // over B*HW
  const int b = pg / HW_, pix = pg % HW_;
  float v[8];
#pragma unroll
  for (int ch = 0; ch < 8; ++ch) v[ch] = xf[((size_t)(b * 8 + ch)) * HW_ + pix];
  float4* dst = reinterpret_cast<float4*>(xfc + (size_t)pg * 8);
  dst[0] = make_float4(v[0], v[1], v[2], v[3]);
  dst[1] = make_float4(v[4], v[5], v[6], v[7]);
}

// ---- weight prep: -> f32, BN fold, transpose to [ci][tap][oc] ----
template<int CIN, int COUT, bool BN>
__global__ __launch_bounds__(256) void prep_k(
    const void* __restrict__ w, const void* __restrict__ p1, const void* __restrict__ p2,
    const void* __restrict__ p3, const void* __restrict__ p4,
    float* __restrict__ wf, float* __restrict__ bfv, const int* __restrict__ flag)
{
  const int f = flag[0];
  const int idx = blockIdx.x * 256 + threadIdx.x;
  if (idx < CIN * 9 * COUT) {
    const int oc = idx % COUT, r = idx / COUT, tap = r % 9, ci = r / 9;
    float s = 1.f;
    if (BN) s = loadf(p1, oc, f) * rsqrtf(loadf(p4, oc, f) + 1e-5f);
    wf[idx] = loadf(w, ((size_t)oc * CIN + ci) * 9 + tap, f) * s;
  }
  if (idx < COUT) {
    float bb;
    if (BN) { float s = loadf(p1, idx, f) * rsqrtf(loadf(p4, idx, f) + 1e-5f); bb = loadf(p2, idx, f) - loadf(p3, idx, f) * s; }
    else bb = loadf(p1, idx, f);
    bfv[idx] = bb;
  }
}

// ---- conv2 weight fragment prep: BN-fold, bf16 hi/lo split, MFMA A-fragment layout ----
__global__ __launch_bounds__(256) void wprep2_k(
    const void* __restrict__ w, const void* __restrict__ p1, const void* __restrict__ p4,
    ushort* __restrict__ wfr, const int* __restrict__ flag)
{
  const int f = flag[0];
  const int idx = blockIdx.x * 256 + threadIdx.x;
  if (idx >= 4608) return;
  const int l = idx & 63, ks = (idx >> 6) % 18, g = idx / 1152;
  const int tap = ks >> 1, s = ks & 1, lg = (l >> 4) & 3, ln = l & 15;
  const int oc = 16 * g + ln;
  const float sc = loadf(p1, oc, f) * rsqrtf(loadf(p4, oc, f) + 1e-5f);
#pragma unroll
  for (int e = 0; e < 8; ++e) {
    const int ci = 32 * s + 8 * lg + e;
    const float wv = loadf(w, ((size_t)oc * 64 + ci) * 9 + tap, f) * sc;
    const ushort hb = bf16rn(wv);
    const float hf = __uint_as_float(((uint)hb) << 16);
    const ushort lb = bf16rn(wv - hf);
    wfr[(((size_t)(g * 18 + ks) * 2 + 0) * 64 + l) * 8 + e] = hb;
    wfr[(((size_t)(g * 18 + ks) * 2 + 1) * 64 + l) * 8 + e] = lb;
  }
}

// ---- fused conv1(8->64, f32) + conv2(64->64, bf16-split MFMA).
// R17: reverted to one net per launch (R16 merge raised L2 pressure: 231us merged
// vs ~195us for two separate launches). ----
__global__ __launch_bounds__(256, 3) void conv12_k(
    const float* __restrict__ xf, const float* __restrict__ wf1,
    const float* __restrict__ b1, const ushort* __restrict__ wfr2,
    const float* __restrict__ b2, float* __restrict__ out)
{
  __shared__ short smem[2 * 13056];        // 52224 B total
  float* raw_s = (float*)smem;             // 9216 B, dead after conv1 regs
  short* c1h = smem;                       // [row6][cib8][col34][cil8]
  short* c1l = smem + 13056;
  const int b = blockIdx.z;
  const int r0 = blockIdx.y * 4, c0 = blockIdx.x * 32;
  const int t = threadIdx.x;
  for (int i = t; i < 8 * 8 * 36; i += 256) {
    const int col = i % 36, rem = i / 36, ci = rem & 7, row = rem >> 3;
    const int gr = r0 - 2 + row, gc = c0 - 2 + col;
    float v = 0.f;
    if (gr >= 0 && gr < H_ && gc >= 0 && gc < W_)
      v = xf[(((size_t)b * C_ + ci) * H_ + gr) * W_ + gc];
    raw_s[i] = v;
  }
  __syncthreads();
  {
    const int w = t >> 6;
    const int h = __builtin_amdgcn_readfirstlane(w & 1);
    const int ps0 = (t & 63) + ((w >> 1) << 6);
    const float* __restrict__ wb = wf1 + 32 * h;
    float a1[2][32];
#pragma unroll
    for (int j = 0; j < 2; ++j)
#pragma unroll
      for (int o = 0; o < 32; ++o) a1[j][o] = 0.f;
    int qv[2], uv[2]; bool pok[2];
#pragma unroll
    for (int j = 0; j < 2; ++j) {
      int p = ps0 + 128 * j;
      pok[j] = p < 204;
      if (!pok[j]) p = 0;
      qv[j] = p / 34; uv[j] = p % 34;
    }
#pragma unroll 1
    for (int ct = 0; ct < 72; ++ct) {
      const int tap = ct % 9, dy = tap / 3, dx = tap % 3;
      float4 w4[8];
#pragma unroll
      for (int o4 = 0; o4 < 8; ++o4)
        w4[o4] = *reinterpret_cast<const float4*>(wb + ct * 64 + 4 * o4);
      const int ci = ct / 9;
#pragma unroll
      for (int j = 0; j < 2; ++j) {
        const float v = raw_s[((qv[j] + dy) * 8 + ci) * 36 + uv[j] + dx];
#pragma unroll
        for (int o4 = 0; o4 < 8; ++o4) {
          a1[j][4*o4+0] = fmaf(v, w4[o4].x, a1[j][4*o4+0]);
          a1[j][4*o4+1] = fmaf(v, w4[o4].y, a1[j][4*o4+1]);
          a1[j][4*o4+2] = fmaf(v, w4[o4].z, a1[j][4*o4+2]);
          a1[j][4*o4+3] = fmaf(v, w4[o4].w, a1[j][4*o4+3]);
        }
      }
    }
    __syncthreads();   // all raw_s reads done before c1 overwrites the union
#pragma unroll
    for (int j = 0; j < 2; ++j) {
      if (pok[j]) {
        const int gr1 = r0 - 1 + qv[j], gc1 = c0 - 1 + uv[j];
        const bool inimg = (gr1 >= 0 && gr1 < H_ && gc1 >= 0 && gc1 < W_);
#pragma unroll
        for (int jb = 0; jb < 4; ++jb) {
          s8v vh, vl;
#pragma unroll
          for (int e = 0; e < 8; ++e) {
            const int o = 8 * jb + e;
            float a = fmaxf(a1[j][o] + b1[32 * h + o], 0.f);
            if (!inimg) a = 0.f;
            const ushort hb = bf16rn(a);
            const float hf = __uint_as_float(((uint)hb) << 16);
            const ushort lb = bf16rn(a - hf);
            vh[e] = (short)hb; vl[e] = (short)lb;
          }
          const int idx = ((qv[j] * 8 + 4 * h + jb) * 34 + uv[j]) * 8;
          *reinterpret_cast<s8v*>(c1h + idx) = vh;
          *reinterpret_cast<s8v*>(c1l + idx) = vl;
        }
      }
    }
  }
  __syncthreads();
  const int l = t & 63;
  const int g = __builtin_amdgcn_readfirstlane(t >> 6);
  const int lg = (l >> 4) & 3, ln = l & 15;
  const int lanebase = (lg * 34 + ln) * 8;
  f4v acc[4][2];
#pragma unroll
  for (int rr = 0; rr < 4; ++rr)
#pragma unroll
    for (int tt = 0; tt < 2; ++tt) acc[rr][tt] = (f4v){0.f, 0.f, 0.f, 0.f};
#pragma unroll
  for (int tt = 0; tt < 2; ++tt)
#pragma unroll
    for (int s = 0; s < 2; ++s)
#pragma unroll
      for (int dc = 0; dc < 3; ++dc) {
        s8v Ah[3], Al[3];
#pragma unroll
        for (int dr = 0; dr < 3; ++dr) {
          const int ks = (3 * dr + dc) * 2 + s;
          Ah[dr] = *reinterpret_cast<const s8v*>(wfr2 + (((size_t)(g * 18 + ks) * 2 + 0) * 64 + l) * 8);
          Al[dr] = *reinterpret_cast<const s8v*>(wfr2 + (((size_t)(g * 18 + ks) * 2 + 1) * 64 + l) * 8);
        }
        s8v Bf[6];
#pragma unroll
        for (int row = 0; row < 6; ++row)
          Bf[row] = *reinterpret_cast<const s8v*>(c1h + ((row * 8 + 4 * s) * 34 + tt * 16 + dc) * 8 + lanebase);
#pragma unroll
        for (int dr = 0; dr < 3; ++dr)
#pragma unroll
          for (int rr = 0; rr < 4; ++rr) {
            acc[rr][tt] = __builtin_amdgcn_mfma_f32_16x16x32_bf16(Ah[dr], Bf[rr + dr], acc[rr][tt], 0, 0, 0);
            acc[rr][tt] = __builtin_amdgcn_mfma_f32_16x16x32_bf16(Al[dr], Bf[rr + dr], acc[rr][tt], 0, 0, 0);
          }
#pragma unroll
        for (int row = 0; row < 6; ++row)
          Bf[row] = *reinterpret_cast<const s8v*>(c1l + ((row * 8 + 4 * s) * 34 + tt * 16 + dc) * 8 + lanebase);
#pragma unroll
        for (int dr = 0; dr < 3; ++dr)
#pragma unroll
          for (int rr = 0; rr < 4; ++rr)
            acc[rr][tt] = __builtin_amdgcn_mfma_f32_16x16x32_bf16(Ah[dr], Bf[rr + dr], acc[rr][tt], 0, 0, 0);
      }
  float b2r[4];
#pragma unroll
  for (int reg = 0; reg < 4; ++reg) b2r[reg] = b2[16 * g + 4 * lg + reg];
#pragma unroll
  for (int rr = 0; rr < 4; ++rr)
#pragma unroll
    for (int tt = 0; tt < 2; ++tt) {
      const int col = c0 + tt * 16 + ln;
      if (col < W_) {
#pragma unroll
        for (int reg = 0; reg < 4; ++reg) {
          const int oc = 16 * g + 4 * lg + reg;
          out[(((size_t)b * 64 + oc) * H_ + r0 + rr) * W_ + col] = fmaxf(acc[rr][tt][reg] + b2r[reg], 0.f);
        }
      }
    }
}

// ---- direct 3x3 SAME conv for small COUT (8 / 1) ----
template<int CIN, int COUT, bool RELU>
__global__ __launch_bounds__(256) void conv3x3_k(
    const float* __restrict__ in, const float* __restrict__ wf,
    const float* __restrict__ bias, float* __restrict__ out)
{
  constexpr int CC = 8;
  __shared__ float in_s[CC][18][18];
  const int b = blockIdx.z;
  const int x0 = blockIdx.x * 16, y0 = blockIdx.y * 16;
  const int t = threadIdx.x, tx = t & 15, ty = t >> 4;
  float acc[COUT];
#pragma unroll
  for (int i = 0; i < COUT; ++i) acc[i] = 0.f;
  for (int ch = 0; ch < CIN / CC; ++ch) {
    __syncthreads();
    for (int idx = t; idx < CC * 324; idx += 256) {
      const int cil = idx / 324, rr = (idx % 324) / 18, cc = idx % 18;
      const int gr = y0 + rr - 1, gc = x0 + cc - 1;
      float v = 0.f;
      if (gr >= 0 && gr < H_ && gc >= 0 && gc < W_)
        v = in[(((size_t)b * CIN + ch * CC + cil) * H_ + gr) * W_ + gc];
      in_s[cil][rr][cc] = v;
    }
    __syncthreads();
#pragma unroll 1
    for (int cil = 0; cil < CC; ++cil) {
      float v[9];
#pragma unroll
      for (int dy = 0; dy < 3; ++dy)
#pragma unroll
        for (int dx = 0; dx < 3; ++dx)
          v[dy * 3 + dx] = in_s[cil][ty + dy][tx + dx];
      const float* wrow = wf + (size_t)(ch * CC + cil) * 9 * COUT;
#pragma unroll
      for (int tap = 0; tap < 9; ++tap)
#pragma unroll
        for (int oc = 0; oc < COUT; ++oc)
          acc[oc] = fmaf(v[tap], wrow[tap * COUT + oc], acc[oc]);
    }
  }
  const int orow = y0 + ty, ocol = x0 + tx;
#pragma unroll
  for (int oc = 0; oc < COUT; ++oc) {
    float r = acc[oc] + bias[oc];
    if (RELU) r = fmaxf(r, 0.f);
    out[(((size_t)b * COUT + oc) * H_ + orow) * W_ + ocol] = r;
  }
}

// ---- per-patch stats ----
__global__ __launch_bounds__(256) void patch_stats_k(
    const float* __restrict__ xe, const float* __restrict__ logt,
    float* __restrict__ ynorm, float* __restrict__ tfac)
{
  __shared__ float red[4];
  const int m = blockIdx.x, b = blockIdx.y, t = threadIdx.x;
  const int gi = m / G_, gj = m % G_;
  const int r0 = gi * S_, c0 = gj * S_;
  float s = 0.f;
  for (int d = t; d < D_; d += 256) {
    const int chn = d / 100, rem = d % 100, pi = rem / 10, pj = rem % 10;
    const float v = xe[(((size_t)b * C_ + chn) * H_ + r0 + pi) * W_ + c0 + pj];
    s += v * v;
  }
  float l = 0.f;
  if (t < 100) l = logt[((size_t)b * H_ + r0 + t / 10) * W_ + c0 + t % 10];
  s = bredsum(s, red, t);
  l = bredsum(l, red, t);
  if (t == 0) { ynorm[b * M_ + m] = s; tfac[b * M_ + m] = expf(-l * 0.01f); }
}

// ---- cell fragment prep ----
__global__ __launch_bounds__(256) void cellprep_k(const float* __restrict__ xe, ushort* __restrict__ cf) {
  const int ci = blockIdx.x, b = blockIdx.y, t = threadIdx.x;
  const size_t base = ((size_t)(b * 48) + ci) * CFSTR_;
  for (int idx = t; idx < 48 * 224; idx += 256) {
    const int cj = idx / 224, k = idx % 224;
    const int ks = k >> 5, r32 = k & 31, lg = r32 >> 3, e = r32 & 7;
    const int chunk = cj >> 4, ln = cj & 15;
    float v = 0.f;
    if (k < 200) {
      const int ch = k / 25, r25 = k % 25, rp = r25 / 5, cp = r25 % 5;
      v = xe[(((size_t)b * C_ + ch) * H_ + ci * 5 + rp) * W_ + cj * 5 + cp];
    }
    const ushort hb = bf16rn(v);
    const float hf = __uint_as_float(((uint)hb) << 16);
    const ushort lb = bf16rn(v - hf);
    const int l = lg * 16 + ln;
    const size_t o = base + ((size_t)((chunk * 7 + ks) * 2) * 64 + l) * 8 + e;
    cf[o] = hb;
    cf[o + 512] = lb;
  }
}

// ---- banded cell Gram via MFMA ----
__global__ __launch_bounds__(192) void gram_k(const ushort* __restrict__ cf, float* __restrict__ Ct) {
  const int blk = blockIdx.x, b = blockIdx.y;
  const int ci = blk / 3, CA = blk % 3;
  const int t = threadIdx.x, l = t & 63;
  const int CB = __builtin_amdgcn_readfirstlane(t >> 6);
  const int lg = (l >> 4) & 3, ln = l & 15;
  const size_t cbase = ((size_t)(b * 48) + ci) * CFSTR_;
  s8v A[14];
#pragma unroll
  for (int ks = 0; ks < 7; ++ks)
#pragma unroll
    for (int hl = 0; hl < 2; ++hl)
      A[ks * 2 + hl] = *reinterpret_cast<const s8v*>(cf + cbase + ((size_t)((CA * 7 + ks) * 2 + hl) * 64 + l) * 8);
  const int dimax = min(14, 47 - ci);
#pragma unroll 1
  for (int di = 0; di <= dimax; ++di) {
    const size_t bbase = cbase + (size_t)di * CFSTR_;
    f4v acc = (f4v){0.f, 0.f, 0.f, 0.f};
#pragma unroll
    for (int ks = 0; ks < 7; ++ks) {
      const s8v Bh = *reinterpret_cast<const s8v*>(cf + bbase + ((size_t)((CB * 7 + ks) * 2 + 0) * 64 + l) * 8);
      const s8v Bl = *reinterpret_cast<const s8v*>(cf + bbase + ((size_t)((CB * 7 + ks) * 2 + 1) * 64 + l) * 8);
      acc = __builtin_amdgcn_mfma_f32_16x16x32_bf16(A[2 * ks], Bh, acc, 0, 0, 0);
      acc = __builtin_amdgcn_mfma_f32_16x16x32_bf16(A[2 * ks + 1], Bh, acc, 0, 0, 0);
      acc = __builtin_amdgcn_mfma_f32_16x16x32_bf16(A[2 * ks], Bl, acc, 0, 0, 0);
      acc = __builtin_amdgcn_mfma_f32_16x16x32_bf16(A[2 * ks + 1], Bl, acc, 0, 0, 0);
    }
    float* __restrict__ Co = Ct + ((size_t)(b * 48 + ci) * 15 + di) * 2304;
#pragma unroll
    for (int reg = 0; reg < 4; ++reg) {
      const int i = CA * 16 + 4 * lg + reg;
      Co[i * 48 + CB * 16 + ln] = acc[reg];
    }
  }
}

// ---- dist v6: dots from Ctab, iterative K-softmax ----
__global__ __launch_bounds__(256) void dist6_k(
    const float* __restrict__ Ct, const float* __restrict__ ynorm,
    const float* __restrict__ tfac, float* __restrict__ Wk)
{
  __shared__ float red[16][17];
  const int tile = blockIdx.x, b = blockIdx.y, t = threadIdx.x;
  const int gi = tile / 3, qj0 = (tile % 3) * 16;
  const int q = t & 15, ni = t >> 4;
  const int nic = (ni < 15) ? ni : 14;
  const int wr0 = wsg(gi);
  const int qj = qj0 + q;
  const bool qok = (qj < G_);
  const int qjc = qok ? qj : G_ - 1;
  const bool act = qok && (ni < 15);
  const int m = gi * G_ + qjc;
  const float ynq = ynorm[b * M_ + m];
  const float tfq = tfac[b * M_ + m];
  const int nr = wr0 + nic;
  const int di = nr - gi;
  const int sgj = wsg(qjc);
  constexpr size_t SLAB = 15 * 2304;
  float logit[15];
#pragma unroll
  for (int dj = 0; dj < 15; ++dj) {
    const int nc = sgj + dj;
    const int nm = nr * G_ + nc;
    const float* p0;
    if (di >= 0)
      p0 = Ct + ((size_t)(b * 48 + gi) * 15 + di) * 2304 + qjc * 48 + nc;
    else
      p0 = Ct + ((size_t)(b * 48 + nr) * 15 + (-di)) * 2304 + nc * 48 + qjc;
    const float dot = p0[0] + p0[49] + p0[SLAB] + p0[SLAB + 49];
    const float Dv = ynq + ynorm[b * M_ + nm] - 2.f * dot;
    logit[dj] = (nm == m) ? -1e9f : -Dv * tfq;
    if (!act) logit[dj] = -3.0e38f;
  }
  const size_t wkb = ((size_t)(b * M_ + m) * K_) * O2_ + nic * 15;
#pragma unroll 1
  for (int k = 0; k < K_; ++k) {
    float pm = -3.0e38f;
#pragma unroll
    for (int dj = 0; dj < 15; ++dj) pm = fmaxf(pm, logit[dj]);
    red[q][ni] = pm;
    __syncthreads();
    float gm = red[q][0];
#pragma unroll
    for (int i = 1; i < 16; ++i) gm = fmaxf(gm, red[q][i]);
    __syncthreads();
    float e[15]; float es = 0.f;
#pragma unroll
    for (int dj = 0; dj < 15; ++dj) { e[dj] = act ? expf(logit[dj] - gm) : 0.f; es += e[dj]; }
    red[q][ni] = es;
    __syncthreads();
    float tot = red[q][0];
#pragma unroll
    for (int i = 1; i < 16; ++i) tot += red[q][i];
    __syncthreads();
    const float inv = 1.f / tot;
#pragma unroll
    for (int dj = 0; dj < 15; ++dj) {
      const float w = e[dj] * inv;
      if (act) Wk[wkb + (size_t)k * O2_ + dj] = w;
      logit[dj] += log1pf(-fminf(w, 1.f - 1e-6f));
    }
  }
}

// ---- A-table assembly ----
__global__ __launch_bounds__(256) void atab_k(const float* __restrict__ Wk, float* __restrict__ A) {
  const int cell = blockIdx.x, b = blockIdx.y, t = threadIdx.x;
  const int ci = cell / NC_, cj = cell % NC_;
  const int di = t >> 4, dj = t & 15;
  const int gi0 = max(ci - 1, 0), gi1 = min(ci, G_ - 1);
  const int gj0 = max(cj - 1, 0), gj1 = min(cj, G_ - 1);
  const int oi0 = wsg(gi0) - gi0, oi1 = wsg(gi1) - gi1;
  const int oj0 = wsg(gj0) - gj0, oj1 = wsg(gj1) - gj1;
  const int bi = min(oi0, oi1), bj = min(oj0, oj1);
  const int wi0 = bi + di - oi0, wi1 = bi + di - oi1;
  const int wj0 = bj + dj - oj0, wj1 = bj + dj - oj1;
  const bool vi0 = (wi0 >= 0 && wi0 < 15);
  const bool vi1 = (gi1 != gi0) && (wi1 >= 0 && wi1 < 15);
  const bool vj0 = (wj0 >= 0 && wj0 < 15);
  const bool vj1 = (gj1 != gj0) && (wj1 >= 0 && wj1 < 15);
  const size_t Wb = (size_t)b * M_ * K_ * O2_;
  const size_t Ab = ((((size_t)(b * NC_ + ci)) * ND_ + di) * NC_ + cj) * ND_ * 7 + dj * 7;
#pragma unroll 1
  for (int k = 0; k < K_; ++k) {
    float s = 0.f;
    if (vi0 && vj0) s += Wk[Wb + ((size_t)(gi0 * G_ + gj0) * K_ + k) * O2_ + wi0 * 15 + wj0];
    if (vi0 && vj1) s += Wk[Wb + ((size_t)(gi0 * G_ + gj1) * K_ + k) * O2_ + wi0 * 15 + wj1];
    if (vi1 && vj0) s += Wk[Wb + ((size_t)(gi1 * G_ + gj0) * K_ + k) * O2_ + wi1 * 15 + wj0];
    if (vi1 && vj1) s += Wk[Wb + ((size_t)(gi1 * G_ + gj1) * K_ + k) * O2_ + wi1 * 15 + wj1];
    A[Ab + k] = s;
  }
}

// ---- aggregation v6: XCD-colocated rows, channels-last x, register prefetch
// of next di's A-slice (R16, kept: loads complete under compute, no barrier stall). ----
__global__ __launch_bounds__(256, 3) void agg3_k(
    const float* __restrict__ xf, const float* __restrict__ xfc,
    const float* __restrict__ A, void* __restrict__ out, const int* __restrict__ flag)
{
  __shared__ float a_s[8448];   // 33792 B: caps residency at 4 blocks/CU
  const int b = blockIdx.y, t = threadIdx.x;
  const int i = blockIdx.x;
  const int xcd = i & 7, slot = i >> 3;
  const int ci = (slot / 5) * 8 + xcd;
  const int r = ci * 5 + slot % 5;
  const int gi0 = max(ci - 1, 0), gi1 = min(ci, G_ - 1);
  const int bi = min(wsg(gi0) - gi0, wsg(gi1) - gi1);
  const int c = t;
  const int cj = (c < W_) ? c / 5 : NC_ - 1;
  const int gj0 = max(cj - 1, 0), gj1 = min(cj, G_ - 1);
  const int bj = min(wsg(gj0) - gj0, wsg(gj1) - gj1);
  const int cbase = c + 5 * bj;
  // staging destinations are di-invariant: hoist the divmods out of the di loop
  int dst[21];
#pragma unroll
  for (int j = 0; j < 21; ++j) {
    const int idx = t + 256 * j;          // 21*256 == 5376 == ASTR_, no guard needed
    const int cjj = idx / 112, rem = idx % 112, dj = rem / 7, kk = rem % 7;
    dst[j] = cjj * 132 + dj * 8 + kk;
  }
  float acc[C_][K_];
#pragma unroll
  for (int ch = 0; ch < C_; ++ch)
#pragma unroll
    for (int k = 0; k < K_; ++k) acc[ch][k] = 0.f;
  const size_t Aslab = (((size_t)(b * NC_ + ci)) * ND_) * ASTR_;
  const float* __restrict__ xcb = xfc + (size_t)b * HW_ * 8;
  // prefetch di=0 into registers
  float rg[21];
  {
    const float* __restrict__ Ag = A + Aslab + t;
#pragma unroll
    for (int j = 0; j < 21; ++j) rg[j] = Ag[256 * j];
  }
#pragma unroll 1
  for (int di = 0; di < ND_; ++di) {
    __syncthreads();                       // prior compute done reading a_s
#pragma unroll
    for (int j = 0; j < 21; ++j) a_s[dst[j]] = rg[j];
    __syncthreads();                       // a_s ready (LDS-only drain)
    if (di + 1 < ND_) {
      const float* __restrict__ Agn = A + Aslab + (size_t)(di + 1) * ASTR_ + t;
#pragma unroll
      for (int j = 0; j < 21; ++j) rg[j] = Agn[256 * j];   // latency hides under compute
    }
    int rp = r + 5 * (bi + di);
    rp = min(max(rp, 0), H_ - 1);
    const float* __restrict__ xrow = xcb + (size_t)rp * (W_ * 8);
    const float* __restrict__ arow = a_s + cj * 132;
#pragma unroll 1
    for (int dj = 0; dj < ND_; ++dj) {
      int cp = cbase + 5 * dj;
      cp = min(max(cp, 0), W_ - 1);
      const float4 x0 = *reinterpret_cast<const float4*>(xrow + cp * 8);
      const float4 x1 = *reinterpret_cast<const float4*>(xrow + cp * 8 + 4);
      const float4 a0 = *reinterpret_cast<const float4*>(arow + dj * 8);
      const float4 a1 = *reinterpret_cast<const float4*>(arow + dj * 8 + 4);
      const float xv[8] = {x0.x, x0.y, x0.z, x0.w, x1.x, x1.y, x1.z, x1.w};
      const float av[7] = {a0.x, a0.y, a0.z, a0.w, a1.x, a1.y, a1.z};
#pragma unroll
      for (int ch = 0; ch < C_; ++ch)
#pragma unroll
        for (int k = 0; k < K_; ++k) acc[ch][k] = fmaf(xv[ch], av[k], acc[ch][k]);
    }
  }
  if (c < W_) {
    const float inv = 1.f / (((r >= S_ && r <= 234) ? 2.f : 1.f) * ((c >= S_ && c <= 234) ? 2.f : 1.f));
    const int isf = flag[0];
    const size_t pix = (size_t)r * W_ + c;
    const float* __restrict__ xb = xf + (size_t)b * C_ * HW_;
#pragma unroll
    for (int ch = 0; ch < C_; ++ch) {
      const float v = xb[(size_t)ch * HW_ + pix];
      const size_t o = ((size_t)b * 64 + ch) * HW_ + pix;
      if (isf) ((float*)out)[o] = v; else ((bf16*)out)[o] = __float2bfloat16(v);
    }
#pragma unroll
    for (int k = 0; k < K_; ++k)
#pragma unroll
      for (int ch = 0; ch < C_; ++ch) {
        const float v = acc[ch][k] * inv;
        const size_t o = ((size_t)b * 64 + 8 + k * C_ + ch) * HW_ + pix;
        if (isf) ((float*)out)[o] = v; else ((bf16*)out)[o] = __float2bfloat16(v);
      }
  }
}

extern "C" void kernel_launch(void* const* d_in, const int* in_sizes, int n_in,
                              void* d_out, int out_size, void* d_ws, size_t ws_size,
                              hipStream_t stream) {
  const void* x = d_in[0];

  float* ws = (float*)d_ws;
  const size_t nH = (size_t)B_ * 64 * HW_;
  const size_t nXE = (size_t)B_ * C_ * HW_;
  const size_t nLT = (size_t)B_ * HW_;
  const size_t nYN = (size_t)B_ * M_;
  size_t off = 0;
  int*   flag  = (int*)(ws + off); off += 4;
  float* xf    = ws + off; off += nXE;
  float* h1    = ws + off; off += nH;
  float* h2    = ws + off; off += nH;
  float* xe    = ws + off; off += nXE;
  float* logt  = ws + off; off += nLT;
  float* ynorm = ws + off; off += nYN;
  float* tfac  = ws + off; off += nYN;
  float* wf1e = ws + off; off += 8 * 9 * 64;
  float* wf2e = ws + off; off += 64 * 9 * 64;
  float* wf3e = ws + off; off += 64 * 9 * 8;
  float* wf1t = ws + off; off += 8 * 9 * 64;
  float* wf2t = ws + off; off += 64 * 9 * 64;
  float* wf3t = ws + off; off += 64 * 9 * 1;
  float* bf1e = ws + off; off += 64;
  float* bf2e = ws + off; off += 64;
  float* bf3e = ws + off; off += 8;
  float* bf1t = ws + off; off += 64;
  float* bf2t = ws + off; off += 64;
  float* bf3t = ws + off; off += 1;
  ushort* wfr2e = (ushort*)(ws + off); off += 36864;
  ushort* wfr2t = (ushort*)(ws + off); off += 36864;
  float* Wk   = h1;                         // t-hidden dead after logt
  float* Ctab = h2;                         // 26.5 MB; h2 dead after xe
  ushort* cellfrag = (ushort*)(h2 + CTSZ_); // 8.3 MB, after Ctab within h2
  float* Atab = h2;                         // overlays Ctab+cellfrag (dead after dist6)
  float* xfc  = h1;                         // channels-last x; overlays Wk (dead after atab)

  detect_k<<<1, 256, 0, stream>>>((const ushort*)x, flag);
  cvt_x_k<<<nXE / 256, 256, 0, stream>>>(x, flag, xf);

  prep_k<8, 64, true ><<<18, 256, 0, stream>>>(d_in[1], d_in[2], d_in[3], d_in[4], d_in[5], wf1e, bf1e, flag);
  prep_k<64, 64, true ><<<144, 256, 0, stream>>>(d_in[6], d_in[7], d_in[8], d_in[9], d_in[10], wf2e, bf2e, flag);
  prep_k<64, 8, false><<<18, 256, 0, stream>>>(d_in[11], d_in[12], nullptr, nullptr, nullptr, wf3e, bf3e, flag);
  prep_k<8, 64, true ><<<18, 256, 0, stream>>>(d_in[13], d_in[14], d_in[15], d_in[16], d_in[17], wf1t, bf1t, flag);
  prep_k<64, 64, true ><<<144, 256, 0, stream>>>(d_in[18], d_in[19], d_in[20], d_in[21], d_in[22], wf2t, bf2t, flag);
  prep_k<64, 1, false><<<3, 256, 0, stream>>>(d_in[23], d_in[24], nullptr, nullptr, nullptr, wf3t, bf3t, flag);
  wprep2_k<<<18, 256, 0, stream>>>(d_in[6], d_in[7], d_in[10], wfr2e, flag);
  wprep2_k<<<18, 256, 0, stream>>>(d_in[18], d_in[19], d_in[22], wfr2t, flag);

  const dim3 gcv(8, 60, B_);
  const dim3 g16(15, 15, B_);
  conv12_k<<<gcv, 256, 0, stream>>>(xf, wf1e, bf1e, wfr2e, bf2e, h2);
  conv3x3_k<64, 8, false><<<g16, 256, 0, stream>>>(h2, wf3e, bf3e, xe);
  conv12_k<<<gcv, 256, 0, stream>>>(xf, wf1t, bf1t, wfr2t, bf2t, h1);
  conv3x3_k<64, 1, false><<<g16, 256, 0, stream>>>(h1, wf3t, bf3t, logt);

  patch_stats_k<<<dim3(M_, B_), 256, 0, stream>>>(xe, logt, ynorm, tfac);
  cellprep_k<<<dim3(48, B_), 256, 0, stream>>>(xe, cellfrag);
  gram_k<<<dim3(144, B_), 192, 0, stream>>>(cellfrag, Ctab);
  dist6_k<<<dim3(G_ * 3, B_), 256, 0, stream>>>(Ctab, ynorm, tfac, Wk);

  atab_k<<<dim3(NC_ * NC_, B_), 256, 0, stream>>>(Wk, Atab);
  cvt2_k<<<(B_ * HW_) / 256, 256, 0, stream>>>(xf, xfc);
  agg3_k<<<dim3(H_, B_), 256, 0, stream>>>(xf, xfc, Atab, d_out, flag);
}

// Round 18
// 792.932 us; speedup vs baseline: 1.0712x; 1.0712x over previous
//
#include <hip/hip_runtime.h>
#include <hip/hip_bf16.h>

using bf16 = __hip_bfloat16;
typedef __attribute__((ext_vector_type(8))) short s8v;
typedef __attribute__((ext_vector_type(4))) float f4v;
#define DEVINL __device__ __forceinline__

constexpr int B_ = 4, C_ = 8, H_ = 240, W_ = 240;
constexpr int P_ = 10, S_ = 5, K_ = 7;
constexpr int G_ = 47, M_ = G_ * G_, O2_ = 225, D_ = 800;
constexpr int HW_ = H_ * W_;
constexpr int NC_ = 48;
constexpr int ND_ = 16;
constexpr int ASTR_ = NC_ * ND_ * 7;
constexpr int CFSTR_ = 3 * 7 * 2 * 512;          // cellfrag shorts per (b,ci) = 21504
constexpr size_t CTSZ_ = (size_t)B_ * 48 * 15 * 2304;   // Ctab floats

DEVINL float loadf(const void* p, size_t i, int isf32) {
  return isf32 ? ((const float*)p)[i] : __bfloat162float(((const bf16*)p)[i]);
}
DEVINL int wsg(int g) { int s = g - 7; if (s < 0) s = 0; if (s > G_ - 15) s = G_ - 15; return s; }
DEVINL ushort bf16rn(float x) {
  uint u = __float_as_uint(x);
  return (ushort)((u + 0x7FFF + ((u >> 16) & 1)) >> 16);
}

// ---- block reductions (256 threads, wave64) ----
DEVINL float bredsum(float v, float* red, int t) {
#pragma unroll
  for (int off = 32; off; off >>= 1) v += __shfl_xor(v, off);
  __syncthreads();
  if ((t & 63) == 0) red[t >> 6] = v;
  __syncthreads();
  return red[0] + red[1] + red[2] + red[3];
}

// ---- dtype detector (flag=1 => f32 inputs) ----
__global__ __launch_bounds__(256) void detect_k(const ushort* __restrict__ xr, int* __restrict__ flag) {
  __shared__ int red[4];
  const int t = threadIdx.x;
  int wild = 0;
  for (int i = t; i < 8192; i += 256) {
    const ushort u = xr[2 * i];
    const int ex = (u >> 7) & 0xFF;
    if (ex == 0xFF || ex > 130 || (ex != 0 && ex < 100)) ++wild;
  }
#pragma unroll
  for (int off = 32; off; off >>= 1) wild += __shfl_xor(wild, off);
  __syncthreads();
  if ((t & 63) == 0) red[t >> 6] = wild;
  __syncthreads();
  if (t == 0) flag[0] = (red[0] + red[1] + red[2] + red[3] > 2048) ? 1 : 0;
}

__global__ __launch_bounds__(256) void cvt_x_k(const void* __restrict__ x, const int* __restrict__ flag,
                                               float* __restrict__ xf) {
  const int i = blockIdx.x * 256 + threadIdx.x;
  xf[i] = loadf(x, i, flag[0]);
}

// ---- channels-last copy: xfc[b][pix][8] from planar xf ----
__global__ __launch_bounds__(256) void cvt2_k(const float* __restrict__ xf, float* __restrict__ xfc) {
  const int pg = blockIdx.x * 256 + threadIdx.x;   // over B*HW
  const int b = pg / HW_, pix = pg % HW_;
  float v[8];
#pragma unroll
  for (int ch = 0; ch < 8; ++ch) v[ch] = xf[((size_t)(b * 8 + ch)) * HW_ + pix];
  float4* dst = reinterpret_cast<float4*>(xfc + (size_t)pg * 8);
  dst[0] = make_float4(v[0], v[1], v[2], v[3]);
  dst[1] = make_float4(v[4], v[5], v[6], v[7]);
}

// ---- weight prep: -> f32, BN fold, transpose to [ci][tap][oc] ----
template<int CIN, int COUT, bool BN>
__global__ __launch_bounds__(256) void prep_k(
    const void* __restrict__ w, const void* __restrict__ p1, const void* __restrict__ p2,
    const void* __restrict__ p3, const void* __restrict__ p4,
    float* __restrict__ wf, float* __restrict__ bfv, const int* __restrict__ flag)
{
  const int f = flag[0];
  const int idx = blockIdx.x * 256 + threadIdx.x;
  if (idx < CIN * 9 * COUT) {
    const int oc = idx % COUT, r = idx / COUT, tap = r % 9, ci = r / 9;
    float s = 1.f;
    if (BN) s = loadf(p1, oc, f) * rsqrtf(loadf(p4, oc, f) + 1e-5f);
    wf[idx] = loadf(w, ((size_t)oc * CIN + ci) * 9 + tap, f) * s;
  }
  if (idx < COUT) {
    float bb;
    if (BN) { float s = loadf(p1, idx, f) * rsqrtf(loadf(p4, idx, f) + 1e-5f); bb = loadf(p2, idx, f) - loadf(p3, idx, f) * s; }
    else bb = loadf(p1, idx, f);
    bfv[idx] = bb;
  }
}

// ---- conv2 weight fragment prep: BN-fold, bf16 hi/lo split, MFMA A-fragment layout ----
__global__ __launch_bounds__(256) void wprep2_k(
    const void* __restrict__ w, const void* __restrict__ p1, const void* __restrict__ p4,
    ushort* __restrict__ wfr, const int* __restrict__ flag)
{
  const int f = flag[0];
  const int idx = blockIdx.x * 256 + threadIdx.x;
  if (idx >= 4608) return;
  const int l = idx & 63, ks = (idx >> 6) % 18, g = idx / 1152;
  const int tap = ks >> 1, s = ks & 1, lg = (l >> 4) & 3, ln = l & 15;
  const int oc = 16 * g + ln;
  const float sc = loadf(p1, oc, f) * rsqrtf(loadf(p4, oc, f) + 1e-5f);
#pragma unroll
  for (int e = 0; e < 8; ++e) {
    const int ci = 32 * s + 8 * lg + e;
    const float wv = loadf(w, ((size_t)oc * 64 + ci) * 9 + tap, f) * sc;
    const ushort hb = bf16rn(wv);
    const float hf = __uint_as_float(((uint)hb) << 16);
    const ushort lb = bf16rn(wv - hf);
    wfr[(((size_t)(g * 18 + ks) * 2 + 0) * 64 + l) * 8 + e] = hb;
    wfr[(((size_t)(g * 18 + ks) * 2 + 1) * 64 + l) * 8 + e] = lb;
  }
}

// ---- fused conv1(8->64, f32) + conv2(64->64, bf16-split MFMA); one net per launch ----
__global__ __launch_bounds__(256, 3) void conv12_k(
    const float* __restrict__ xf, const float* __restrict__ wf1,
    const float* __restrict__ b1, const ushort* __restrict__ wfr2,
    const float* __restrict__ b2, float* __restrict__ out)
{
  __shared__ short smem[2 * 13056];        // 52224 B total
  float* raw_s = (float*)smem;             // 9216 B, dead after conv1 regs
  short* c1h = smem;                       // [row6][cib8][col34][cil8]
  short* c1l = smem + 13056;
  const int b = blockIdx.z;
  const int r0 = blockIdx.y * 4, c0 = blockIdx.x * 32;
  const int t = threadIdx.x;
  for (int i = t; i < 8 * 8 * 36; i += 256) {
    const int col = i % 36, rem = i / 36, ci = rem & 7, row = rem >> 3;
    const int gr = r0 - 2 + row, gc = c0 - 2 + col;
    float v = 0.f;
    if (gr >= 0 && gr < H_ && gc >= 0 && gc < W_)
      v = xf[(((size_t)b * C_ + ci) * H_ + gr) * W_ + gc];
    raw_s[i] = v;
  }
  __syncthreads();
  {
    const int w = t >> 6;
    const int h = __builtin_amdgcn_readfirstlane(w & 1);
    const int ps0 = (t & 63) + ((w >> 1) << 6);
    const float* __restrict__ wb = wf1 + 32 * h;
    float a1[2][32];
#pragma unroll
    for (int j = 0; j < 2; ++j)
#pragma unroll
      for (int o = 0; o < 32; ++o) a1[j][o] = 0.f;
    int qv[2], uv[2]; bool pok[2];
#pragma unroll
    for (int j = 0; j < 2; ++j) {
      int p = ps0 + 128 * j;
      pok[j] = p < 204;
      if (!pok[j]) p = 0;
      qv[j] = p / 34; uv[j] = p % 34;
    }
#pragma unroll 1
    for (int ct = 0; ct < 72; ++ct) {
      const int tap = ct % 9, dy = tap / 3, dx = tap % 3;
      float4 w4[8];
#pragma unroll
      for (int o4 = 0; o4 < 8; ++o4)
        w4[o4] = *reinterpret_cast<const float4*>(wb + ct * 64 + 4 * o4);
      const int ci = ct / 9;
#pragma unroll
      for (int j = 0; j < 2; ++j) {
        const float v = raw_s[((qv[j] + dy) * 8 + ci) * 36 + uv[j] + dx];
#pragma unroll
        for (int o4 = 0; o4 < 8; ++o4) {
          a1[j][4*o4+0] = fmaf(v, w4[o4].x, a1[j][4*o4+0]);
          a1[j][4*o4+1] = fmaf(v, w4[o4].y, a1[j][4*o4+1]);
          a1[j][4*o4+2] = fmaf(v, w4[o4].z, a1[j][4*o4+2]);
          a1[j][4*o4+3] = fmaf(v, w4[o4].w, a1[j][4*o4+3]);
        }
      }
    }
    __syncthreads();   // all raw_s reads done before c1 overwrites the union
#pragma unroll
    for (int j = 0; j < 2; ++j) {
      if (pok[j]) {
        const int gr1 = r0 - 1 + qv[j], gc1 = c0 - 1 + uv[j];
        const bool inimg = (gr1 >= 0 && gr1 < H_ && gc1 >= 0 && gc1 < W_);
#pragma unroll
        for (int jb = 0; jb < 4; ++jb) {
          s8v vh, vl;
#pragma unroll
          for (int e = 0; e < 8; ++e) {
            const int o = 8 * jb + e;
            float a = fmaxf(a1[j][o] + b1[32 * h + o], 0.f);
            if (!inimg) a = 0.f;
            const ushort hb = bf16rn(a);
            const float hf = __uint_as_float(((uint)hb) << 16);
            const ushort lb = bf16rn(a - hf);
            vh[e] = (short)hb; vl[e] = (short)lb;
          }
          const int idx = ((qv[j] * 8 + 4 * h + jb) * 34 + uv[j]) * 8;
          *reinterpret_cast<s8v*>(c1h + idx) = vh;
          *reinterpret_cast<s8v*>(c1l + idx) = vl;
        }
      }
    }
  }
  __syncthreads();
  const int l = t & 63;
  const int g = __builtin_amdgcn_readfirstlane(t >> 6);
  const int lg = (l >> 4) & 3, ln = l & 15;
  const int lanebase = (lg * 34 + ln) * 8;
  f4v acc[4][2];
#pragma unroll
  for (int rr = 0; rr < 4; ++rr)
#pragma unroll
    for (int tt = 0; tt < 2; ++tt) acc[rr][tt] = (f4v){0.f, 0.f, 0.f, 0.f};
#pragma unroll
  for (int tt = 0; tt < 2; ++tt)
#pragma unroll
    for (int s = 0; s < 2; ++s)
#pragma unroll
      for (int dc = 0; dc < 3; ++dc) {
        s8v Ah[3], Al[3];
#pragma unroll
        for (int dr = 0; dr < 3; ++dr) {
          const int ks = (3 * dr + dc) * 2 + s;
          Ah[dr] = *reinterpret_cast<const s8v*>(wfr2 + (((size_t)(g * 18 + ks) * 2 + 0) * 64 + l) * 8);
          Al[dr] = *reinterpret_cast<const s8v*>(wfr2 + (((size_t)(g * 18 + ks) * 2 + 1) * 64 + l) * 8);
        }
        s8v Bf[6];
#pragma unroll
        for (int row = 0; row < 6; ++row)
          Bf[row] = *reinterpret_cast<const s8v*>(c1h + ((row * 8 + 4 * s) * 34 + tt * 16 + dc) * 8 + lanebase);
#pragma unroll
        for (int dr = 0; dr < 3; ++dr)
#pragma unroll
          for (int rr = 0; rr < 4; ++rr) {
            acc[rr][tt] = __builtin_amdgcn_mfma_f32_16x16x32_bf16(Ah[dr], Bf[rr + dr], acc[rr][tt], 0, 0, 0);
            acc[rr][tt] = __builtin_amdgcn_mfma_f32_16x16x32_bf16(Al[dr], Bf[rr + dr], acc[rr][tt], 0, 0, 0);
          }
#pragma unroll
        for (int row = 0; row < 6; ++row)
          Bf[row] = *reinterpret_cast<const s8v*>(c1l + ((row * 8 + 4 * s) * 34 + tt * 16 + dc) * 8 + lanebase);
#pragma unroll
        for (int dr = 0; dr < 3; ++dr)
#pragma unroll
          for (int rr = 0; rr < 4; ++rr)
            acc[rr][tt] = __builtin_amdgcn_mfma_f32_16x16x32_bf16(Ah[dr], Bf[rr + dr], acc[rr][tt], 0, 0, 0);
      }
  float b2r[4];
#pragma unroll
  for (int reg = 0; reg < 4; ++reg) b2r[reg] = b2[16 * g + 4 * lg + reg];
#pragma unroll
  for (int rr = 0; rr < 4; ++rr)
#pragma unroll
    for (int tt = 0; tt < 2; ++tt) {
      const int col = c0 + tt * 16 + ln;
      if (col < W_) {
#pragma unroll
        for (int reg = 0; reg < 4; ++reg) {
          const int oc = 16 * g + 4 * lg + reg;
          out[(((size_t)b * 64 + oc) * H_ + r0 + rr) * W_ + col] = fmaxf(acc[rr][tt][reg] + b2r[reg], 0.f);
        }
      }
    }
}

// ---- direct 3x3 SAME conv for small COUT (8 / 1) ----
template<int CIN, int COUT, bool RELU>
__global__ __launch_bounds__(256) void conv3x3_k(
    const float* __restrict__ in, const float* __restrict__ wf,
    const float* __restrict__ bias, float* __restrict__ out)
{
  constexpr int CC = 8;
  __shared__ float in_s[CC][18][18];
  const int b = blockIdx.z;
  const int x0 = blockIdx.x * 16, y0 = blockIdx.y * 16;
  const int t = threadIdx.x, tx = t & 15, ty = t >> 4;
  float acc[COUT];
#pragma unroll
  for (int i = 0; i < COUT; ++i) acc[i] = 0.f;
  for (int ch = 0; ch < CIN / CC; ++ch) {
    __syncthreads();
    for (int idx = t; idx < CC * 324; idx += 256) {
      const int cil = idx / 324, rr = (idx % 324) / 18, cc = idx % 18;
      const int gr = y0 + rr - 1, gc = x0 + cc - 1;
      float v = 0.f;
      if (gr >= 0 && gr < H_ && gc >= 0 && gc < W_)
        v = in[(((size_t)b * CIN + ch * CC + cil) * H_ + gr) * W_ + gc];
      in_s[cil][rr][cc] = v;
    }
    __syncthreads();
#pragma unroll 1
    for (int cil = 0; cil < CC; ++cil) {
      float v[9];
#pragma unroll
      for (int dy = 0; dy < 3; ++dy)
#pragma unroll
        for (int dx = 0; dx < 3; ++dx)
          v[dy * 3 + dx] = in_s[cil][ty + dy][tx + dx];
      const float* wrow = wf + (size_t)(ch * CC + cil) * 9 * COUT;
#pragma unroll
      for (int tap = 0; tap < 9; ++tap)
#pragma unroll
        for (int oc = 0; oc < COUT; ++oc)
          acc[oc] = fmaf(v[tap], wrow[tap * COUT + oc], acc[oc]);
    }
  }
  const int orow = y0 + ty, ocol = x0 + tx;
#pragma unroll
  for (int oc = 0; oc < COUT; ++oc) {
    float r = acc[oc] + bias[oc];
    if (RELU) r = fmaxf(r, 0.f);
    out[(((size_t)b * COUT + oc) * H_ + orow) * W_ + ocol] = r;
  }
}

// ---- per-patch stats ----
__global__ __launch_bounds__(256) void patch_stats_k(
    const float* __restrict__ xe, const float* __restrict__ logt,
    float* __restrict__ ynorm, float* __restrict__ tfac)
{
  __shared__ float red[4];
  const int m = blockIdx.x, b = blockIdx.y, t = threadIdx.x;
  const int gi = m / G_, gj = m % G_;
  const int r0 = gi * S_, c0 = gj * S_;
  float s = 0.f;
  for (int d = t; d < D_; d += 256) {
    const int chn = d / 100, rem = d % 100, pi = rem / 10, pj = rem % 10;
    const float v = xe[(((size_t)b * C_ + chn) * H_ + r0 + pi) * W_ + c0 + pj];
    s += v * v;
  }
  float l = 0.f;
  if (t < 100) l = logt[((size_t)b * H_ + r0 + t / 10) * W_ + c0 + t % 10];
  s = bredsum(s, red, t);
  l = bredsum(l, red, t);
  if (t == 0) { ynorm[b * M_ + m] = s; tfac[b * M_ + m] = expf(-l * 0.01f); }
}

// ---- cell fragment prep ----
__global__ __launch_bounds__(256) void cellprep_k(const float* __restrict__ xe, ushort* __restrict__ cf) {
  const int ci = blockIdx.x, b = blockIdx.y, t = threadIdx.x;
  const size_t base = ((size_t)(b * 48) + ci) * CFSTR_;
  for (int idx = t; idx < 48 * 224; idx += 256) {
    const int cj = idx / 224, k = idx % 224;
    const int ks = k >> 5, r32 = k & 31, lg = r32 >> 3, e = r32 & 7;
    const int chunk = cj >> 4, ln = cj & 15;
    float v = 0.f;
    if (k < 200) {
      const int ch = k / 25, r25 = k % 25, rp = r25 / 5, cp = r25 % 5;
      v = xe[(((size_t)b * C_ + ch) * H_ + ci * 5 + rp) * W_ + cj * 5 + cp];
    }
    const ushort hb = bf16rn(v);
    const float hf = __uint_as_float(((uint)hb) << 16);
    const ushort lb = bf16rn(v - hf);
    const int l = lg * 16 + ln;
    const size_t o = base + ((size_t)((chunk * 7 + ks) * 2) * 64 + l) * 8 + e;
    cf[o] = hb;
    cf[o + 512] = lb;
  }
}

// ---- banded cell Gram via MFMA ----
__global__ __launch_bounds__(192) void gram_k(const ushort* __restrict__ cf, float* __restrict__ Ct) {
  const int blk = blockIdx.x, b = blockIdx.y;
  const int ci = blk / 3, CA = blk % 3;
  const int t = threadIdx.x, l = t & 63;
  const int CB = __builtin_amdgcn_readfirstlane(t >> 6);
  const int lg = (l >> 4) & 3, ln = l & 15;
  const size_t cbase = ((size_t)(b * 48) + ci) * CFSTR_;
  s8v A[14];
#pragma unroll
  for (int ks = 0; ks < 7; ++ks)
#pragma unroll
    for (int hl = 0; hl < 2; ++hl)
      A[ks * 2 + hl] = *reinterpret_cast<const s8v*>(cf + cbase + ((size_t)((CA * 7 + ks) * 2 + hl) * 64 + l) * 8);
  const int dimax = min(14, 47 - ci);
#pragma unroll 1
  for (int di = 0; di <= dimax; ++di) {
    const size_t bbase = cbase + (size_t)di * CFSTR_;
    f4v acc = (f4v){0.f, 0.f, 0.f, 0.f};
#pragma unroll
    for (int ks = 0; ks < 7; ++ks) {
      const s8v Bh = *reinterpret_cast<const s8v*>(cf + bbase + ((size_t)((CB * 7 + ks) * 2 + 0) * 64 + l) * 8);
      const s8v Bl = *reinterpret_cast<const s8v*>(cf + bbase + ((size_t)((CB * 7 + ks) * 2 + 1) * 64 + l) * 8);
      acc = __builtin_amdgcn_mfma_f32_16x16x32_bf16(A[2 * ks], Bh, acc, 0, 0, 0);
      acc = __builtin_amdgcn_mfma_f32_16x16x32_bf16(A[2 * ks + 1], Bh, acc, 0, 0, 0);
      acc = __builtin_amdgcn_mfma_f32_16x16x32_bf16(A[2 * ks], Bl, acc, 0, 0, 0);
      acc = __builtin_amdgcn_mfma_f32_16x16x32_bf16(A[2 * ks + 1], Bl, acc, 0, 0, 0);
    }
    float* __restrict__ Co = Ct + ((size_t)(b * 48 + ci) * 15 + di) * 2304;
#pragma unroll
    for (int reg = 0; reg < 4; ++reg) {
      const int i = CA * 16 + 4 * lg + reg;
      Co[i * 48 + CB * 16 + ln] = acc[reg];
    }
  }
}

// ---- dist v6: dots from Ctab, iterative K-softmax ----
__global__ __launch_bounds__(256) void dist6_k(
    const float* __restrict__ Ct, const float* __restrict__ ynorm,
    const float* __restrict__ tfac, float* __restrict__ Wk)
{
  __shared__ float red[16][17];
  const int tile = blockIdx.x, b = blockIdx.y, t = threadIdx.x;
  const int gi = tile / 3, qj0 = (tile % 3) * 16;
  const int q = t & 15, ni = t >> 4;
  const int nic = (ni < 15) ? ni : 14;
  const int wr0 = wsg(gi);
  const int qj = qj0 + q;
  const bool qok = (qj < G_);
  const int qjc = qok ? qj : G_ - 1;
  const bool act = qok && (ni < 15);
  const int m = gi * G_ + qjc;
  const float ynq = ynorm[b * M_ + m];
  const float tfq = tfac[b * M_ + m];
  const int nr = wr0 + nic;
  const int di = nr - gi;
  const int sgj = wsg(qjc);
  constexpr size_t SLAB = 15 * 2304;
  float logit[15];
#pragma unroll
  for (int dj = 0; dj < 15; ++dj) {
    const int nc = sgj + dj;
    const int nm = nr * G_ + nc;
    const float* p0;
    if (di >= 0)
      p0 = Ct + ((size_t)(b * 48 + gi) * 15 + di) * 2304 + qjc * 48 + nc;
    else
      p0 = Ct + ((size_t)(b * 48 + nr) * 15 + (-di)) * 2304 + nc * 48 + qjc;
    const float dot = p0[0] + p0[49] + p0[SLAB] + p0[SLAB + 49];
    const float Dv = ynq + ynorm[b * M_ + nm] - 2.f * dot;
    logit[dj] = (nm == m) ? -1e9f : -Dv * tfq;
    if (!act) logit[dj] = -3.0e38f;
  }
  const size_t wkb = ((size_t)(b * M_ + m) * K_) * O2_ + nic * 15;
#pragma unroll 1
  for (int k = 0; k < K_; ++k) {
    float pm = -3.0e38f;
#pragma unroll
    for (int dj = 0; dj < 15; ++dj) pm = fmaxf(pm, logit[dj]);
    red[q][ni] = pm;
    __syncthreads();
    float gm = red[q][0];
#pragma unroll
    for (int i = 1; i < 16; ++i) gm = fmaxf(gm, red[q][i]);
    __syncthreads();
    float e[15]; float es = 0.f;
#pragma unroll
    for (int dj = 0; dj < 15; ++dj) { e[dj] = act ? expf(logit[dj] - gm) : 0.f; es += e[dj]; }
    red[q][ni] = es;
    __syncthreads();
    float tot = red[q][0];
#pragma unroll
    for (int i = 1; i < 16; ++i) tot += red[q][i];
    __syncthreads();
    const float inv = 1.f / tot;
#pragma unroll
    for (int dj = 0; dj < 15; ++dj) {
      const float w = e[dj] * inv;
      if (act) Wk[wkb + (size_t)k * O2_ + dj] = w;
      logit[dj] += log1pf(-fminf(w, 1.f - 1e-6f));
    }
  }
}

// ---- A-table assembly ----
__global__ __launch_bounds__(256) void atab_k(const float* __restrict__ Wk, float* __restrict__ A) {
  const int cell = blockIdx.x, b = blockIdx.y, t = threadIdx.x;
  const int ci = cell / NC_, cj = cell % NC_;
  const int di = t >> 4, dj = t & 15;
  const int gi0 = max(ci - 1, 0), gi1 = min(ci, G_ - 1);
  const int gj0 = max(cj - 1, 0), gj1 = min(cj, G_ - 1);
  const int oi0 = wsg(gi0) - gi0, oi1 = wsg(gi1) - gi1;
  const int oj0 = wsg(gj0) - gj0, oj1 = wsg(gj1) - gj1;
  const int bi = min(oi0, oi1), bj = min(oj0, oj1);
  const int wi0 = bi + di - oi0, wi1 = bi + di - oi1;
  const int wj0 = bj + dj - oj0, wj1 = bj + dj - oj1;
  const bool vi0 = (wi0 >= 0 && wi0 < 15);
  const bool vi1 = (gi1 != gi0) && (wi1 >= 0 && wi1 < 15);
  const bool vj0 = (wj0 >= 0 && wj0 < 15);
  const bool vj1 = (gj1 != gj0) && (wj1 >= 0 && wj1 < 15);
  const size_t Wb = (size_t)b * M_ * K_ * O2_;
  const size_t Ab = ((((size_t)(b * NC_ + ci)) * ND_ + di) * NC_ + cj) * ND_ * 7 + dj * 7;
#pragma unroll 1
  for (int k = 0; k < K_; ++k) {
    float s = 0.f;
    if (vi0 && vj0) s += Wk[Wb + ((size_t)(gi0 * G_ + gj0) * K_ + k) * O2_ + wi0 * 15 + wj0];
    if (vi0 && vj1) s += Wk[Wb + ((size_t)(gi0 * G_ + gj1) * K_ + k) * O2_ + wi0 * 15 + wj1];
    if (vi1 && vj0) s += Wk[Wb + ((size_t)(gi1 * G_ + gj0) * K_ + k) * O2_ + wi1 * 15 + wj0];
    if (vi1 && vj1) s += Wk[Wb + ((size_t)(gi1 * G_ + gj1) * K_ + k) * O2_ + wi1 * 15 + wj1];
    A[Ab + k] = s;
  }
}

// ---- aggregation v4 (best measured, R14/R15): XCD-colocated rows, channels-last x,
// divmod-hoisted staging, LDS pad; NO register prefetch (R17 A/B: prefetch = +50us). ----
__global__ __launch_bounds__(256, 4) void agg3_k(
    const float* __restrict__ xf, const float* __restrict__ xfc,
    const float* __restrict__ A, void* __restrict__ out, const int* __restrict__ flag)
{
  __shared__ float a_s[8448];   // 33792 B: caps residency at 4 blocks/CU
  const int b = blockIdx.y, t = threadIdx.x;
  const int i = blockIdx.x;
  const int xcd = i & 7, slot = i >> 3;
  const int ci = (slot / 5) * 8 + xcd;
  const int r = ci * 5 + slot % 5;
  const int gi0 = max(ci - 1, 0), gi1 = min(ci, G_ - 1);
  const int bi = min(wsg(gi0) - gi0, wsg(gi1) - gi1);
  const int c = t;
  const int cj = (c < W_) ? c / 5 : NC_ - 1;
  const int gj0 = max(cj - 1, 0), gj1 = min(cj, G_ - 1);
  const int bj = min(wsg(gj0) - gj0, wsg(gj1) - gj1);
  const int cbase = c + 5 * bj;
  // staging destinations are di-invariant: hoist the divmods out of the di loop
  int dst[21];
#pragma unroll
  for (int j = 0; j < 21; ++j) {
    const int idx = t + 256 * j;          // 21*256 == 5376 == ASTR_, no guard needed
    const int cjj = idx / 112, rem = idx % 112, dj = rem / 7, kk = rem % 7;
    dst[j] = cjj * 132 + dj * 8 + kk;
  }
  float acc[C_][K_];
#pragma unroll
  for (int ch = 0; ch < C_; ++ch)
#pragma unroll
    for (int k = 0; k < K_; ++k) acc[ch][k] = 0.f;
  const size_t Aslab = (((size_t)(b * NC_ + ci)) * ND_) * ASTR_;
  const float* __restrict__ xcb = xfc + (size_t)b * HW_ * 8;
#pragma unroll 1
  for (int di = 0; di < ND_; ++di) {
    __syncthreads();
    const float* __restrict__ Ag = A + Aslab + (size_t)di * ASTR_ + t;
#pragma unroll
    for (int j = 0; j < 21; ++j)
      a_s[dst[j]] = Ag[256 * j];
    __syncthreads();
    int rp = r + 5 * (bi + di);
    rp = min(max(rp, 0), H_ - 1);
    const float* __restrict__ xrow = xcb + (size_t)rp * (W_ * 8);
    const float* __restrict__ arow = a_s + cj * 132;
#pragma unroll 1
    for (int dj = 0; dj < ND_; ++dj) {
      int cp = cbase + 5 * dj;
      cp = min(max(cp, 0), W_ - 1);
      const float4 x0 = *reinterpret_cast<const float4*>(xrow + cp * 8);
      const float4 x1 = *reinterpret_cast<const float4*>(xrow + cp * 8 + 4);
      const float4 a0 = *reinterpret_cast<const float4*>(arow + dj * 8);
      const float4 a1 = *reinterpret_cast<const float4*>(arow + dj * 8 + 4);
      const float xv[8] = {x0.x, x0.y, x0.z, x0.w, x1.x, x1.y, x1.z, x1.w};
      const float av[7] = {a0.x, a0.y, a0.z, a0.w, a1.x, a1.y, a1.z};
#pragma unroll
      for (int ch = 0; ch < C_; ++ch)
#pragma unroll
        for (int k = 0; k < K_; ++k) acc[ch][k] = fmaf(xv[ch], av[k], acc[ch][k]);
    }
  }
  if (c < W_) {
    const float inv = 1.f / (((r >= S_ && r <= 234) ? 2.f : 1.f) * ((c >= S_ && c <= 234) ? 2.f : 1.f));
    const int isf = flag[0];
    const size_t pix = (size_t)r * W_ + c;
    const float* __restrict__ xb = xf + (size_t)b * C_ * HW_;
#pragma unroll
    for (int ch = 0; ch < C_; ++ch) {
      const float v = xb[(size_t)ch * HW_ + pix];
      const size_t o = ((size_t)b * 64 + ch) * HW_ + pix;
      if (isf) ((float*)out)[o] = v; else ((bf16*)out)[o] = __float2bfloat16(v);
    }
#pragma unroll
    for (int k = 0; k < K_; ++k)
#pragma unroll
      for (int ch = 0; ch < C_; ++ch) {
        const float v = acc[ch][k] * inv;
        const size_t o = ((size_t)b * 64 + 8 + k * C_ + ch) * HW_ + pix;
        if (isf) ((float*)out)[o] = v; else ((bf16*)out)[o] = __float2bfloat16(v);
      }
  }
}

extern "C" void kernel_launch(void* const* d_in, const int* in_sizes, int n_in,
                              void* d_out, int out_size, void* d_ws, size_t ws_size,
                              hipStream_t stream) {
  const void* x = d_in[0];

  float* ws = (float*)d_ws;
  const size_t nH = (size_t)B_ * 64 * HW_;
  const size_t nXE = (size_t)B_ * C_ * HW_;
  const size_t nLT = (size_t)B_ * HW_;
  const size_t nYN = (size_t)B_ * M_;
  size_t off = 0;
  int*   flag  = (int*)(ws + off); off += 4;
  float* xf    = ws + off; off += nXE;
  float* h1    = ws + off; off += nH;
  float* h2    = ws + off; off += nH;
  float* xe    = ws + off; off += nXE;
  float* logt  = ws + off; off += nLT;
  float* ynorm = ws + off; off += nYN;
  float* tfac  = ws + off; off += nYN;
  float* wf1e = ws + off; off += 8 * 9 * 64;
  float* wf2e = ws + off; off += 64 * 9 * 64;
  float* wf3e = ws + off; off += 64 * 9 * 8;
  float* wf1t = ws + off; off += 8 * 9 * 64;
  float* wf2t = ws + off; off += 64 * 9 * 64;
  float* wf3t = ws + off; off += 64 * 9 * 1;
  float* bf1e = ws + off; off += 64;
  float* bf2e = ws + off; off += 64;
  float* bf3e = ws + off; off += 8;
  float* bf1t = ws + off; off += 64;
  float* bf2t = ws + off; off += 64;
  float* bf3t = ws + off; off += 1;
  ushort* wfr2e = (ushort*)(ws + off); off += 36864;
  ushort* wfr2t = (ushort*)(ws + off); off += 36864;
  float* Wk   = h1;                         // t-hidden dead after logt
  float* Ctab = h2;                         // 26.5 MB; h2 dead after xe
  ushort* cellfrag = (ushort*)(h2 + CTSZ_); // 8.3 MB, after Ctab within h2
  float* Atab = h2;                         // overlays Ctab+cellfrag (dead after dist6)
  float* xfc  = h1;                         // channels-last x; overlays Wk (dead after atab)

  detect_k<<<1, 256, 0, stream>>>((const ushort*)x, flag);
  cvt_x_k<<<nXE / 256, 256, 0, stream>>>(x, flag, xf);

  prep_k<8, 64, true ><<<18, 256, 0, stream>>>(d_in[1], d_in[2], d_in[3], d_in[4], d_in[5], wf1e, bf1e, flag);
  prep_k<64, 64, true ><<<144, 256, 0, stream>>>(d_in[6], d_in[7], d_in[8], d_in[9], d_in[10], wf2e, bf2e, flag);
  prep_k<64, 8, false><<<18, 256, 0, stream>>>(d_in[11], d_in[12], nullptr, nullptr, nullptr, wf3e, bf3e, flag);
  prep_k<8, 64, true ><<<18, 256, 0, stream>>>(d_in[13], d_in[14], d_in[15], d_in[16], d_in[17], wf1t, bf1t, flag);
  prep_k<64, 64, true ><<<144, 256, 0, stream>>>(d_in[18], d_in[19], d_in[20], d_in[21], d_in[22], wf2t, bf2t, flag);
  prep_k<64, 1, false><<<3, 256, 0, stream>>>(d_in[23], d_in[24], nullptr, nullptr, nullptr, wf3t, bf3t, flag);
  wprep2_k<<<18, 256, 0, stream>>>(d_in[6], d_in[7], d_in[10], wfr2e, flag);
  wprep2_k<<<18, 256, 0, stream>>>(d_in[18], d_in[19], d_in[22], wfr2t, flag);

  const dim3 gcv(8, 60, B_);
  const dim3 g16(15, 15, B_);
  conv12_k<<<gcv, 256, 0, stream>>>(xf, wf1e, bf1e, wfr2e, bf2e, h2);
  conv3x3_k<64, 8, false><<<g16, 256, 0, stream>>>(h2, wf3e, bf3e, xe);
  conv12_k<<<gcv, 256, 0, stream>>>(xf, wf1t, bf1t, wfr2t, bf2t, h1);
  conv3x3_k<64, 1, false><<<g16, 256, 0, stream>>>(h1, wf3t, bf3t, logt);

  patch_stats_k<<<dim3(M_, B_), 256, 0, stream>>>(xe, logt, ynorm, tfac);
  cellprep_k<<<dim3(48, B_), 256, 0, stream>>>(xe, cellfrag);
  gram_k<<<dim3(144, B_), 192, 0, stream>>>(cellfrag, Ctab);
  dist6_k<<<dim3(G_ * 3, B_), 256, 0, stream>>>(Ctab, ynorm, tfac, Wk);

  atab_k<<<dim3(NC_ * NC_, B_), 256, 0, stream>>>(Wk, Atab);
  cvt2_k<<<(B_ * HW_) / 256, 256, 0, stream>>>(xf, xfc);
  agg3_k<<<dim3(H_, B_), 256, 0, stream>>>(xf, xfc, Atab, d_out, flag);
}